// Round 3
// baseline (422.531 us; speedup 1.0000x reference)
//
#include <hip/hip_runtime.h>
#include <math.h>

#define IMW 512
#define IMH 512
#define NPIX (IMW * IMH)
#define TR 16      // output rows per wave
#define OW 116     // output cols per tile
#define C1F 1.0e-4f
#define C2F 9.0e-4f
#define NBLK (5 * 8 * 96)

struct Weights { float w[11]; };

__global__ __launch_bounds__(256, 4)
void ssim_l1_kernel(const float* __restrict__ warped,
                    const float* __restrict__ target,
                    float2* __restrict__ partial,
                    Weights wt)
{
    const int lane = threadIdx.x & 63;
    const int wv   = threadIdx.x >> 6;     // wave 0..3
    const int bx    = blockIdx.x;          // 0..4
    const int by    = blockIdx.y;          // 0..7
    const int plane = blockIdx.z;          // 0..95

    const int c0 = bx * OW;                // output cols [c0, c0+OW)
    const int r0 = (by * 4 + wv) * TR;     // output rows [r0, r0+TR)
    const int c  = c0 - 6 + 2 * lane;      // first input col this lane owns (even)
    const bool laneIn = (c >= 0) && (c < IMW);   // even width => both comps share this

    // L1 mask: input col within the tile's output range (exactly-once partition)
    const bool l1ok = (lane >= 3) && (lane <= 60) && (c < IMW);
    // SSIM output cols: o1 = c0+2*lane-1, o2 = c0+2*lane
    const int o1 = c0 + 2 * lane - 1;
    const int o2 = o1 + 1;
    const bool ok1 = (lane >= 1) && (lane <= 58) && (o1 < IMW);
    const bool ok2 = (lane <= 57) && (o2 < IMW);

    const size_t base = (size_t)plane * NPIX;
    const float2* xp = (const float2*)(warped + base);
    const float2* yp = (const float2*)(target + base);
    const int cHalf = c >> 1;              // float2 index

    // sliding 11-row windows of float2: x, y, x^2+y^2, x*y
    float2 W0[11], W1[11], W2[11], W3[11];
    float l1sum = 0.0f, ssum = 0.0f;

    #pragma unroll
    for (int i = 0; i < TR + 10; ++i) {
        const int rr = r0 - 5 + i;
        const bool ok = laneIn && (rr >= 0) && (rr < IMH);
        float2 x = make_float2(0.f, 0.f), y = make_float2(0.f, 0.f);
        if (ok) {
            x = xp[rr * (IMW / 2) + cHalf];
            y = yp[rr * (IMW / 2) + cHalf];
        }
        const int slot = i % 11;
        W0[slot] = x;
        W1[slot] = y;
        W2[slot] = make_float2(fmaf(x.x, x.x, y.x * y.x), fmaf(x.y, x.y, y.y * y.y));
        W3[slot] = make_float2(x.x * y.x, x.y * y.y);

        if (i >= 10) {
            const int tt = i - 10;
            // ---- vertical blur (registers) ----
            float2 v0 = make_float2(0.f, 0.f), v1 = v0, v2 = v0, v3 = v0;
            #pragma unroll
            for (int k = 0; k < 11; ++k) {
                const int s = (tt + k) % 11;   // static after unroll
                const float wk = wt.w[k];
                v0.x = fmaf(wk, W0[s].x, v0.x); v0.y = fmaf(wk, W0[s].y, v0.y);
                v1.x = fmaf(wk, W1[s].x, v1.x); v1.y = fmaf(wk, W1[s].y, v1.y);
                v2.x = fmaf(wk, W2[s].x, v2.x); v2.y = fmaf(wk, W2[s].y, v2.y);
                v3.x = fmaf(wk, W3[s].x, v3.x); v3.y = fmaf(wk, W3[s].y, v3.y);
            }

            // ---- horizontal blur via cross-lane shuffle (5 srcs, 2 comps each) ----
            float2 hh[4];
            #pragma unroll
            for (int q = 0; q < 4; ++q) {
                const float2 vq = (q == 0) ? v0 : (q == 1) ? v1 : (q == 2) ? v2 : v3;
                float g[12];
                g[0] = vq.x; g[1] = vq.y;
                #pragma unroll
                for (int s = 1; s <= 5; ++s) {
                    g[2 * s]     = __shfl(vq.x, lane + s);
                    g[2 * s + 1] = __shfl(vq.y, lane + s);
                }
                float h1 = 0.f, h2 = 0.f;
                #pragma unroll
                for (int d = 0; d < 11; ++d) {
                    const float wk = wt.w[d];
                    h1 = fmaf(wk, g[d],     h1);
                    h2 = fmaf(wk, g[d + 1], h2);
                }
                hh[q] = make_float2(h1, h2);
            }

            // ---- L1 at center row ----
            if (l1ok) {
                const int s5 = (i - 5) % 11;   // static after unroll
                l1sum += fabsf(W0[s5].x - W1[s5].x) + fabsf(W0[s5].y - W1[s5].y);
            }

            // ---- SSIM map (2 output cols) ----
            #pragma unroll
            for (int e = 0; e < 2; ++e) {
                const bool okx = (e == 0) ? ok1 : ok2;
                if (okx) {
                    const float mu1 = (e == 0) ? hh[0].x : hh[0].y;
                    const float mu2 = (e == 0) ? hh[1].x : hh[1].y;
                    const float sq  = (e == 0) ? hh[2].x : hh[2].y;
                    const float sxy = (e == 0) ? hh[3].x : hh[3].y;
                    const float mu1sq = mu1 * mu1;
                    const float mu2sq = mu2 * mu2;
                    const float mu12  = mu1 * mu2;
                    const float s12   = sxy - mu12;
                    const float ssig  = sq - mu1sq - mu2sq;   // sigma1^2 + sigma2^2
                    const float num = (2.0f * mu12 + C1F) * (2.0f * s12 + C2F);
                    const float den = (mu1sq + mu2sq + C1F) * (ssig + C2F);
                    ssum = fmaf(num, __builtin_amdgcn_rcpf(den), ssum);
                }
            }
        }
    }

    // ---- wave reduction ----
    #pragma unroll
    for (int off = 32; off > 0; off >>= 1) {
        l1sum += __shfl_down(l1sum, off);
        ssum  += __shfl_down(ssum,  off);
    }

    // ---- block reduction ----
    __shared__ float red[8];
    if (lane == 0) { red[wv] = l1sum; red[4 + wv] = ssum; }
    __syncthreads();
    if (threadIdx.x == 0) {
        const float L1 = red[0] + red[1] + red[2] + red[3];
        const float SS = red[4] + red[5] + red[6] + red[7];
        const int bid = (blockIdx.z * gridDim.y + blockIdx.y) * gridDim.x + blockIdx.x;
        partial[bid] = make_float2(L1, SS);
    }
}

__global__ __launch_bounds__(256)
void reduce_kernel(const float2* __restrict__ partial, float* __restrict__ out)
{
    double l1 = 0.0, ss = 0.0;
    for (int i = threadIdx.x; i < NBLK; i += 256) {
        const float2 p = partial[i];
        l1 += (double)p.x;
        ss += (double)p.y;
    }
    #pragma unroll
    for (int off = 32; off > 0; off >>= 1) {
        l1 += __shfl_down(l1, off);
        ss += __shfl_down(ss, off);
    }
    __shared__ double red[8];
    const int wv = threadIdx.x >> 6, lane = threadIdx.x & 63;
    if (lane == 0) { red[wv] = l1; red[4 + wv] = ss; }
    __syncthreads();
    if (threadIdx.x == 0) {
        const double n = 25165824.0;   // 32*3*512*512
        const double L1 = (red[0] + red[1] + red[2] + red[3]) / n;
        const double SS = (red[4] + red[5] + red[6] + red[7]) / n;
        out[0] = (float)(0.5 * L1 + 0.5 * (1.0 - SS));
    }
}

extern "C" void kernel_launch(void* const* d_in, const int* in_sizes, int n_in,
                              void* d_out, int out_size, void* d_ws, size_t ws_size,
                              hipStream_t stream)
{
    const float* warped = (const float*)d_in[0];
    const float* target = (const float*)d_in[1];
    float* out      = (float*)d_out;
    float2* partial = (float2*)d_ws;

    // Gaussian window (f32, same as reference)
    Weights wt;
    float g[11], sum = 0.0f;
    for (int i = 0; i < 11; ++i) {
        const float cc = (float)(i - 5);
        g[i] = expf(-(cc * cc) / (2.0f * 1.5f * 1.5f));
        sum += g[i];
    }
    for (int i = 0; i < 11; ++i) wt.w[i] = g[i] / sum;

    dim3 grid(5, 8, 96);    // x-tiles(116 cols) × y-groups(4 waves × 16 rows) × planes
    dim3 block(256);
    hipLaunchKernelGGL(ssim_l1_kernel, grid, block, 0, stream,
                       warped, target, partial, wt);
    hipLaunchKernelGGL(reduce_kernel, dim3(1), dim3(256), 0, stream, partial, out);
}

// Round 4
// 161.128 us; speedup vs baseline: 2.6223x; 2.6223x over previous
//
#include <hip/hip_runtime.h>
#include <math.h>

#define IMW 512
#define IMH 512
#define NPIX (IMW * IMH)
#define TR 16      // output rows per wave
#define OW 116     // output cols per tile
#define C1F 1.0e-4f
#define C2F 9.0e-4f
#define NBLK (5 * 8 * 96)

struct Weights { float w[11]; };

__global__ __launch_bounds__(256)
void ssim_l1_kernel(const float* __restrict__ warped,
                    const float* __restrict__ target,
                    float2* __restrict__ partial,
                    Weights wt)
{
    const int lane = threadIdx.x & 63;
    const int wv   = threadIdx.x >> 6;     // wave 0..3
    const int bx    = blockIdx.x;          // 0..4
    const int by    = blockIdx.y;          // 0..7
    const int plane = blockIdx.z;          // 0..95

    const int c0 = bx * OW;                // output cols [c0, c0+OW)
    const int r0 = (by * 4 + wv) * TR;     // output rows [r0, r0+TR)
    const int c  = c0 - 6 + 2 * lane;      // first input col this lane owns (even)
    const bool laneIn = (c >= 0) && (c < IMW);

    // L1 mask: input col within the tile's output range (exactly-once partition)
    const bool l1ok = (lane >= 3) && (lane <= 60) && (c < IMW);
    // SSIM output cols: o1 = c0+2*lane-1, o2 = c0+2*lane
    const int o1 = c0 + 2 * lane - 1;
    const int o2 = o1 + 1;
    const bool ok1 = (lane >= 1) && (lane <= 58) && (o1 < IMW);
    const bool ok2 = (lane <= 57) && (o2 < IMW);

    const size_t base = (size_t)plane * NPIX;
    const float2* xp = (const float2*)(warped + base);
    const float2* yp = (const float2*)(target + base);
    const int cHalf = c >> 1;              // float2 index

    // sliding 11-row windows of float2: x, y, x^2+y^2, x*y
    float2 W0[11], W1[11], W2[11], W3[11];
    float l1sum = 0.0f, ssum = 0.0f;

    #pragma unroll
    for (int i = 0; i < TR + 10; ++i) {
        const int rr = r0 - 5 + i;
        const bool ok = laneIn && (rr >= 0) && (rr < IMH);
        float2 x = make_float2(0.f, 0.f), y = make_float2(0.f, 0.f);
        if (ok) {
            x = xp[rr * (IMW / 2) + cHalf];
            y = yp[rr * (IMW / 2) + cHalf];
        }
        const int slot = i % 11;
        W0[slot] = x;
        W1[slot] = y;
        W2[slot] = make_float2(fmaf(x.x, x.x, y.x * y.x), fmaf(x.y, x.y, y.y * y.y));
        W3[slot] = make_float2(x.x * y.x, x.y * y.y);

        if (i >= 10) {
            const int tt = i - 10;
            // ---- vertical blur (registers) ----
            float2 v0 = make_float2(0.f, 0.f), v1 = v0, v2 = v0, v3 = v0;
            #pragma unroll
            for (int k = 0; k < 11; ++k) {
                const int s = (tt + k) % 11;   // static after unroll
                const float wk = wt.w[k];
                v0.x = fmaf(wk, W0[s].x, v0.x); v0.y = fmaf(wk, W0[s].y, v0.y);
                v1.x = fmaf(wk, W1[s].x, v1.x); v1.y = fmaf(wk, W1[s].y, v1.y);
                v2.x = fmaf(wk, W2[s].x, v2.x); v2.y = fmaf(wk, W2[s].y, v2.y);
                v3.x = fmaf(wk, W3[s].x, v3.x); v3.y = fmaf(wk, W3[s].y, v3.y);
            }

            // ---- horizontal blur via cross-lane shuffle (5 srcs, 2 comps each) ----
            float2 hh[4];
            #pragma unroll
            for (int q = 0; q < 4; ++q) {
                const float2 vq = (q == 0) ? v0 : (q == 1) ? v1 : (q == 2) ? v2 : v3;
                float g[12];
                g[0] = vq.x; g[1] = vq.y;
                #pragma unroll
                for (int s = 1; s <= 5; ++s) {
                    g[2 * s]     = __shfl(vq.x, lane + s);
                    g[2 * s + 1] = __shfl(vq.y, lane + s);
                }
                float h1 = 0.f, h2 = 0.f;
                #pragma unroll
                for (int d = 0; d < 11; ++d) {
                    const float wk = wt.w[d];
                    h1 = fmaf(wk, g[d],     h1);
                    h2 = fmaf(wk, g[d + 1], h2);
                }
                hh[q] = make_float2(h1, h2);
            }

            // ---- L1 at center row ----
            if (l1ok) {
                const int s5 = (i - 5) % 11;   // static after unroll
                l1sum += fabsf(W0[s5].x - W1[s5].x) + fabsf(W0[s5].y - W1[s5].y);
            }

            // ---- SSIM map (2 output cols) ----
            #pragma unroll
            for (int e = 0; e < 2; ++e) {
                const bool okx = (e == 0) ? ok1 : ok2;
                if (okx) {
                    const float mu1 = (e == 0) ? hh[0].x : hh[0].y;
                    const float mu2 = (e == 0) ? hh[1].x : hh[1].y;
                    const float sq  = (e == 0) ? hh[2].x : hh[2].y;
                    const float sxy = (e == 0) ? hh[3].x : hh[3].y;
                    const float mu1sq = mu1 * mu1;
                    const float mu2sq = mu2 * mu2;
                    const float mu12  = mu1 * mu2;
                    const float s12   = sxy - mu12;
                    const float ssig  = sq - mu1sq - mu2sq;   // sigma1^2 + sigma2^2
                    const float num = (2.0f * mu12 + C1F) * (2.0f * s12 + C2F);
                    const float den = (mu1sq + mu2sq + C1F) * (ssig + C2F);
                    ssum = fmaf(num, __builtin_amdgcn_rcpf(den), ssum);
                }
            }
        }
    }

    // ---- wave reduction ----
    #pragma unroll
    for (int off = 32; off > 0; off >>= 1) {
        l1sum += __shfl_down(l1sum, off);
        ssum  += __shfl_down(ssum,  off);
    }

    // ---- block reduction ----
    __shared__ float red[8];
    if (lane == 0) { red[wv] = l1sum; red[4 + wv] = ssum; }
    __syncthreads();
    if (threadIdx.x == 0) {
        const float L1 = red[0] + red[1] + red[2] + red[3];
        const float SS = red[4] + red[5] + red[6] + red[7];
        const int bid = (blockIdx.z * gridDim.y + blockIdx.y) * gridDim.x + blockIdx.x;
        partial[bid] = make_float2(L1, SS);
    }
}

__global__ __launch_bounds__(256)
void reduce_kernel(const float2* __restrict__ partial, float* __restrict__ out)
{
    double l1 = 0.0, ss = 0.0;
    for (int i = threadIdx.x; i < NBLK; i += 256) {
        const float2 p = partial[i];
        l1 += (double)p.x;
        ss += (double)p.y;
    }
    #pragma unroll
    for (int off = 32; off > 0; off >>= 1) {
        l1 += __shfl_down(l1, off);
        ss += __shfl_down(ss, off);
    }
    __shared__ double red[8];
    const int wv = threadIdx.x >> 6, lane = threadIdx.x & 63;
    if (lane == 0) { red[wv] = l1; red[4 + wv] = ss; }
    __syncthreads();
    if (threadIdx.x == 0) {
        const double n = 25165824.0;   // 32*3*512*512
        const double L1 = (red[0] + red[1] + red[2] + red[3]) / n;
        const double SS = (red[4] + red[5] + red[6] + red[7]) / n;
        out[0] = (float)(0.5 * L1 + 0.5 * (1.0 - SS));
    }
}

extern "C" void kernel_launch(void* const* d_in, const int* in_sizes, int n_in,
                              void* d_out, int out_size, void* d_ws, size_t ws_size,
                              hipStream_t stream)
{
    const float* warped = (const float*)d_in[0];
    const float* target = (const float*)d_in[1];
    float* out      = (float*)d_out;
    float2* partial = (float2*)d_ws;

    // Gaussian window (f32, same as reference)
    Weights wt;
    float g[11], sum = 0.0f;
    for (int i = 0; i < 11; ++i) {
        const float cc = (float)(i - 5);
        g[i] = expf(-(cc * cc) / (2.0f * 1.5f * 1.5f));
        sum += g[i];
    }
    for (int i = 0; i < 11; ++i) wt.w[i] = g[i] / sum;

    dim3 grid(5, 8, 96);    // x-tiles(116 cols) × y-groups(4 waves × 16 rows) × planes
    dim3 block(256);
    hipLaunchKernelGGL(ssim_l1_kernel, grid, block, 0, stream,
                       warped, target, partial, wt);
    hipLaunchKernelGGL(reduce_kernel, dim3(1), dim3(256), 0, stream, partial, out);
}

// Round 5
// 142.969 us; speedup vs baseline: 2.9554x; 1.1270x over previous
//
#include <hip/hip_runtime.h>
#include <math.h>

#define IMW 512
#define IMH 512
#define NPIX (IMW * IMH)
#define TR 32      // output rows per wave
#define OW 116     // output cols per tile
#define NITER (TR + 10)   // 42 row iterations
#define C1F 1.0e-4f
#define C2F 9.0e-4f
#define NBLK (5 * 4 * 96)

struct Weights { float w[11]; };

__global__ __launch_bounds__(256)
void ssim_l1_kernel(const float* __restrict__ warped,
                    const float* __restrict__ target,
                    float2* __restrict__ partial,
                    Weights wt)
{
    const int lane = threadIdx.x & 63;
    const int wv   = threadIdx.x >> 6;     // wave 0..3
    const int bx    = blockIdx.x;          // 0..4
    const int by    = blockIdx.y;          // 0..3
    const int plane = blockIdx.z;          // 0..95

    const int c0 = bx * OW;                // output cols [c0, c0+OW)
    const int r0 = (by * 4 + wv) * TR;     // output rows [r0, r0+TR)
    const int c  = c0 - 6 + 2 * lane;      // first input col this lane owns (even)
    const float colMask = (c >= 0 && c < IMW) ? 1.0f : 0.0f;
    const int chc = min(max(c >> 1, 0), IMW / 2 - 1);   // clamped float2 index

    // L1 mask: input col within the tile's output range (exactly-once partition)
    const bool l1ok = (lane >= 3) && (lane <= 60) && (c < IMW);
    // SSIM output cols: o1 = c0+2*lane-1, o2 = c0+2*lane
    const int o1 = c0 + 2 * lane - 1;
    const int o2 = o1 + 1;
    const bool ok1 = (lane >= 1) && (lane <= 58) && (o1 < IMW);
    const bool ok2 = (lane <= 57) && (o2 < IMW);

    const size_t base = (size_t)plane * NPIX;
    const float2* xp = (const float2*)(warped + base);
    const float2* yp = (const float2*)(target + base);

    // 12-slot sliding windows (slot = i % 12, static under 12-unroll):
    // W0=x, W1=y, W2=x^2+y^2, W3=x*y
    float2 W0[12], W1[12], W2[12], W3[12];
    float l1sum = 0.0f, ssum = 0.0f;

    // prologue: issue load for iteration 0 (row r0-5, clamped; masked at consume)
    int rp = min(max(r0 - 5, 0), IMH - 1);
    float2 fx = xp[rp * (IMW / 2) + chc];
    float2 fy = yp[rp * (IMW / 2) + chc];

    #pragma unroll 1
    for (int ob = 0; ob < 48; ob += 12) {
        #pragma unroll
        for (int jj = 0; jj < 12; ++jj) {
            const int i = ob + jj;        // uniform (scalar) across wave
            if (i < NITER) {
                // ---- consume pending load -> window slot jj ----
                const int rr = r0 - 5 + i;
                const float msk = (rr >= 0 && rr < IMH) ? colMask : 0.0f;
                const float2 x = make_float2(fx.x * msk, fx.y * msk);
                const float2 y = make_float2(fy.x * msk, fy.y * msk);
                W0[jj] = x;
                W1[jj] = y;
                W2[jj] = make_float2(fmaf(x.x, x.x, y.x * y.x),
                                     fmaf(x.y, x.y, y.y * y.y));
                W3[jj] = make_float2(x.x * y.x, x.y * y.y);

                // ---- L1 at consume time (rows r0..r0+TR-1 <-> i in [5, TR+5)) ----
                if (i >= 5 && i < TR + 5) {
                    if (l1ok) l1sum += fabsf(x.x - y.x) + fabsf(x.y - y.y);
                }

                // ---- prefetch next row (branchless, clamped) ----
                if (i + 1 < NITER) {
                    const int rn = min(max(r0 - 4 + i, 0), IMH - 1);
                    fx = xp[rn * (IMW / 2) + chc];
                    fy = yp[rn * (IMW / 2) + chc];
                }

                // ---- blur + SSIM for output row r0 + (i-10) ----
                if (i >= 10) {
                    // vertical blur: tap k (0..10) -> slot (jj+2+k)%12 (static)
                    float2 v0 = make_float2(0.f, 0.f), v1 = v0, v2 = v0, v3 = v0;
                    #pragma unroll
                    for (int k = 0; k < 11; ++k) {
                        const int s = (jj + 2 + k) % 12;
                        const float wk = wt.w[k];
                        v0.x = fmaf(wk, W0[s].x, v0.x); v0.y = fmaf(wk, W0[s].y, v0.y);
                        v1.x = fmaf(wk, W1[s].x, v1.x); v1.y = fmaf(wk, W1[s].y, v1.y);
                        v2.x = fmaf(wk, W2[s].x, v2.x); v2.y = fmaf(wk, W2[s].y, v2.y);
                        v3.x = fmaf(wk, W3[s].x, v3.x); v3.y = fmaf(wk, W3[s].y, v3.y);
                    }

                    // horizontal blur via cross-lane shuffle (5 srcs, 2 comps each)
                    float2 hh[4];
                    #pragma unroll
                    for (int q = 0; q < 4; ++q) {
                        const float2 vq = (q == 0) ? v0 : (q == 1) ? v1 : (q == 2) ? v2 : v3;
                        float g[12];
                        g[0] = vq.x; g[1] = vq.y;
                        #pragma unroll
                        for (int s = 1; s <= 5; ++s) {
                            g[2 * s]     = __shfl(vq.x, lane + s);
                            g[2 * s + 1] = __shfl(vq.y, lane + s);
                        }
                        float h1 = 0.f, h2 = 0.f;
                        #pragma unroll
                        for (int d = 0; d < 11; ++d) {
                            const float wk = wt.w[d];
                            h1 = fmaf(wk, g[d],     h1);
                            h2 = fmaf(wk, g[d + 1], h2);
                        }
                        hh[q] = make_float2(h1, h2);
                    }

                    // SSIM map (2 output cols)
                    #pragma unroll
                    for (int e = 0; e < 2; ++e) {
                        const bool okx = (e == 0) ? ok1 : ok2;
                        if (okx) {
                            const float mu1 = (e == 0) ? hh[0].x : hh[0].y;
                            const float mu2 = (e == 0) ? hh[1].x : hh[1].y;
                            const float sq  = (e == 0) ? hh[2].x : hh[2].y;
                            const float sxy = (e == 0) ? hh[3].x : hh[3].y;
                            const float mu1sq = mu1 * mu1;
                            const float mu2sq = mu2 * mu2;
                            const float mu12  = mu1 * mu2;
                            const float s12   = sxy - mu12;
                            const float ssig  = sq - mu1sq - mu2sq;  // s1^2+s2^2
                            const float num = (2.0f * mu12 + C1F) * (2.0f * s12 + C2F);
                            const float den = (mu1sq + mu2sq + C1F) * (ssig + C2F);
                            ssum = fmaf(num, __builtin_amdgcn_rcpf(den), ssum);
                        }
                    }
                }
            }
        }
    }

    // ---- wave reduction ----
    #pragma unroll
    for (int off = 32; off > 0; off >>= 1) {
        l1sum += __shfl_down(l1sum, off);
        ssum  += __shfl_down(ssum,  off);
    }

    // ---- block reduction ----
    __shared__ float red[8];
    if (lane == 0) { red[wv] = l1sum; red[4 + wv] = ssum; }
    __syncthreads();
    if (threadIdx.x == 0) {
        const float L1 = red[0] + red[1] + red[2] + red[3];
        const float SS = red[4] + red[5] + red[6] + red[7];
        const int bid = (blockIdx.z * gridDim.y + blockIdx.y) * gridDim.x + blockIdx.x;
        partial[bid] = make_float2(L1, SS);
    }
}

__global__ __launch_bounds__(256)
void reduce_kernel(const float2* __restrict__ partial, float* __restrict__ out)
{
    double l1 = 0.0, ss = 0.0;
    for (int i = threadIdx.x; i < NBLK; i += 256) {
        const float2 p = partial[i];
        l1 += (double)p.x;
        ss += (double)p.y;
    }
    #pragma unroll
    for (int off = 32; off > 0; off >>= 1) {
        l1 += __shfl_down(l1, off);
        ss += __shfl_down(ss, off);
    }
    __shared__ double red[8];
    const int wv = threadIdx.x >> 6, lane = threadIdx.x & 63;
    if (lane == 0) { red[wv] = l1; red[4 + wv] = ss; }
    __syncthreads();
    if (threadIdx.x == 0) {
        const double n = 25165824.0;   // 32*3*512*512
        const double L1 = (red[0] + red[1] + red[2] + red[3]) / n;
        const double SS = (red[4] + red[5] + red[6] + red[7]) / n;
        out[0] = (float)(0.5 * L1 + 0.5 * (1.0 - SS));
    }
}

extern "C" void kernel_launch(void* const* d_in, const int* in_sizes, int n_in,
                              void* d_out, int out_size, void* d_ws, size_t ws_size,
                              hipStream_t stream)
{
    const float* warped = (const float*)d_in[0];
    const float* target = (const float*)d_in[1];
    float* out      = (float*)d_out;
    float2* partial = (float2*)d_ws;

    // Gaussian window (f32, same as reference)
    Weights wt;
    float g[11], sum = 0.0f;
    for (int i = 0; i < 11; ++i) {
        const float cc = (float)(i - 5);
        g[i] = expf(-(cc * cc) / (2.0f * 1.5f * 1.5f));
        sum += g[i];
    }
    for (int i = 0; i < 11; ++i) wt.w[i] = g[i] / sum;

    dim3 grid(5, 4, 96);    // x-tiles(116 cols) × y-groups(4 waves × 32 rows) × planes
    dim3 block(256);
    hipLaunchKernelGGL(ssim_l1_kernel, grid, block, 0, stream,
                       warped, target, partial, wt);
    hipLaunchKernelGGL(reduce_kernel, dim3(1), dim3(256), 0, stream, partial, out);
}

// Round 6
// 134.250 us; speedup vs baseline: 3.1474x; 1.0650x over previous
//
#include <hip/hip_runtime.h>
#include <math.h>

#define IMW 512
#define IMH 512
#define NPIX (IMW * IMH)
#define TR 32      // output rows per wave
#define OW 116     // output cols per tile
#define NITER (TR + 10)   // 42 row iterations
#define C1F 1.0e-4f
#define C2F 9.0e-4f
#define NBLK (5 * 4 * 96)

struct Weights { float w[11]; };

__global__ __launch_bounds__(256)
void ssim_l1_kernel(const float* __restrict__ warped,
                    const float* __restrict__ target,
                    float2* __restrict__ partial,
                    Weights wt)
{
    // per-wave private LDS: [wave][row-parity][quantity][float2 col 0..67]
    // stored col n (input col - c0) at float index n+6 (0..127); 68 float2 = 136 floats
    __shared__ float2 LDS2[4][2][4][68];
    __shared__ float red[8];

    const int lane = threadIdx.x & 63;
    const int wv   = threadIdx.x >> 6;     // wave 0..3
    const int bx    = blockIdx.x;          // 0..4
    const int by    = blockIdx.y;          // 0..3
    const int plane = blockIdx.z;          // 0..95

    const int c0 = bx * OW;                // output cols [c0, c0+OW)
    const int r0 = (by * 4 + wv) * TR;     // output rows [r0, r0+TR)
    const int c  = c0 - 6 + 2 * lane;      // first input col this lane owns (even)
    const float colMask = (c >= 0 && c < IMW) ? 1.0f : 0.0f;
    const int chc = min(max(c >> 1, 0), IMW / 2 - 1);   // clamped float2 index

    // L1 mask: input col within the tile's output range (exactly-once partition)
    const bool l1ok = (lane >= 3) && (lane <= 60) && (c < IMW);
    // SSIM output cols: o1 = c0+2*lane-1, o2 = c0+2*lane
    const int o1 = c0 + 2 * lane - 1;
    const int o2 = o1 + 1;
    const bool ok1 = (lane >= 1) && (lane <= 58) && (o1 < IMW);
    const bool ok2 = (lane <= 57) && (o2 < IMW);
    const int Mr = min(lane, 58);          // clamped read index (keeps reads in-bounds)

    const size_t base = (size_t)plane * NPIX;
    const float2* xp = (const float2*)(warped + base);
    const float2* yp = (const float2*)(target + base);

    // 12-slot sliding windows (slot = i % 12, static under 12-unroll):
    // W0=x, W1=y, W2=x^2+y^2, W3=x*y
    float2 W0[12], W1[12], W2[12], W3[12];
    float l1sum = 0.0f, ssum = 0.0f;

    // prologue: issue load for iteration 0 (row r0-5, clamped; masked at consume)
    int rp = min(max(r0 - 5, 0), IMH - 1);
    float2 fx = xp[rp * (IMW / 2) + chc];
    float2 fy = yp[rp * (IMW / 2) + chc];

    #pragma unroll 1
    for (int ob = 0; ob < 48; ob += 12) {
        #pragma unroll
        for (int jj = 0; jj < 12; ++jj) {
            const int i = ob + jj;        // uniform (scalar) across wave
            if (i < NITER) {
                // ---- consume pending load -> window slot jj ----
                const int rr = r0 - 5 + i;
                const float msk = (rr >= 0 && rr < IMH) ? colMask : 0.0f;
                const float2 x = make_float2(fx.x * msk, fx.y * msk);
                const float2 y = make_float2(fy.x * msk, fy.y * msk);
                W0[jj] = x;
                W1[jj] = y;
                W2[jj] = make_float2(fmaf(x.x, x.x, y.x * y.x),
                                     fmaf(x.y, x.y, y.y * y.y));
                W3[jj] = make_float2(x.x * y.x, x.y * y.y);

                // ---- L1 at consume time (rows r0..r0+TR-1 <-> i in [5, TR+5)) ----
                if (i >= 5 && i < TR + 5) {
                    if (l1ok) l1sum += fabsf(x.x - y.x) + fabsf(x.y - y.y);
                }

                // ---- prefetch next row (branchless, clamped) ----
                if (i + 1 < NITER) {
                    const int rn = min(max(r0 - 4 + i, 0), IMH - 1);
                    fx = xp[rn * (IMW / 2) + chc];
                    fy = yp[rn * (IMW / 2) + chc];
                }

                // ---- vertical blur + LDS round-trip + horizontal + SSIM ----
                if (i >= 10) {
                    const int par = (i - 10) & 1;   // row parity (double buffer)

                    // vertical blur: tap k (0..10) -> slot (jj+2+k)%12 (static)
                    float2 v0 = make_float2(0.f, 0.f), v1 = v0, v2 = v0, v3 = v0;
                    #pragma unroll
                    for (int k = 0; k < 11; ++k) {
                        const int s = (jj + 2 + k) % 12;
                        const float wk = wt.w[k];
                        v0.x = fmaf(wk, W0[s].x, v0.x); v0.y = fmaf(wk, W0[s].y, v0.y);
                        v1.x = fmaf(wk, W1[s].x, v1.x); v1.y = fmaf(wk, W1[s].y, v1.y);
                        v2.x = fmaf(wk, W2[s].x, v2.x); v2.y = fmaf(wk, W2[s].y, v2.y);
                        v3.x = fmaf(wk, W3[s].x, v3.x); v3.y = fmaf(wk, W3[s].y, v3.y);
                    }

                    // write vertical results: lane L holds cols idx 2L,2L+1 -> float2 idx L
                    LDS2[wv][par][0][lane] = v0;
                    LDS2[wv][par][1][lane] = v1;
                    LDS2[wv][par][2][lane] = v2;
                    LDS2[wv][par][3][lane] = v3;

                    // read 12 taps (6 float2) per quantity, compute h-blur, SSIM
                    float2 hh[4];
                    #pragma unroll
                    for (int q = 0; q < 4; ++q) {
                        float g[12];
                        #pragma unroll
                        for (int j = 0; j < 6; ++j) {
                            const float2 t2 = LDS2[wv][par][q][Mr + j];
                            g[2 * j]     = t2.x;
                            g[2 * j + 1] = t2.y;
                        }
                        float h1 = 0.f, h2 = 0.f;
                        #pragma unroll
                        for (int d = 0; d < 11; ++d) {
                            const float wk = wt.w[d];
                            h1 = fmaf(wk, g[d],     h1);
                            h2 = fmaf(wk, g[d + 1], h2);
                        }
                        hh[q] = make_float2(h1, h2);
                    }

                    // SSIM map (2 output cols)
                    #pragma unroll
                    for (int e = 0; e < 2; ++e) {
                        const bool okx = (e == 0) ? ok1 : ok2;
                        if (okx) {
                            const float mu1 = (e == 0) ? hh[0].x : hh[0].y;
                            const float mu2 = (e == 0) ? hh[1].x : hh[1].y;
                            const float sq  = (e == 0) ? hh[2].x : hh[2].y;
                            const float sxy = (e == 0) ? hh[3].x : hh[3].y;
                            const float mu1sq = mu1 * mu1;
                            const float mu2sq = mu2 * mu2;
                            const float mu12  = mu1 * mu2;
                            const float s12   = sxy - mu12;
                            const float ssig  = sq - mu1sq - mu2sq;  // s1^2+s2^2
                            const float num = (2.0f * mu12 + C1F) * (2.0f * s12 + C2F);
                            const float den = (mu1sq + mu2sq + C1F) * (ssig + C2F);
                            ssum = fmaf(num, __builtin_amdgcn_rcpf(den), ssum);
                        }
                    }
                }
            }
        }
    }

    // ---- wave reduction ----
    #pragma unroll
    for (int off = 32; off > 0; off >>= 1) {
        l1sum += __shfl_down(l1sum, off);
        ssum  += __shfl_down(ssum,  off);
    }

    // ---- block reduction ----
    if (lane == 0) { red[wv] = l1sum; red[4 + wv] = ssum; }
    __syncthreads();
    if (threadIdx.x == 0) {
        const float L1 = red[0] + red[1] + red[2] + red[3];
        const float SS = red[4] + red[5] + red[6] + red[7];
        const int bid = (blockIdx.z * gridDim.y + blockIdx.y) * gridDim.x + blockIdx.x;
        partial[bid] = make_float2(L1, SS);
    }
}

__global__ __launch_bounds__(256)
void reduce_kernel(const float2* __restrict__ partial, float* __restrict__ out)
{
    double l1 = 0.0, ss = 0.0;
    for (int i = threadIdx.x; i < NBLK; i += 256) {
        const float2 p = partial[i];
        l1 += (double)p.x;
        ss += (double)p.y;
    }
    #pragma unroll
    for (int off = 32; off > 0; off >>= 1) {
        l1 += __shfl_down(l1, off);
        ss += __shfl_down(ss, off);
    }
    __shared__ double red[8];
    const int wv = threadIdx.x >> 6, lane = threadIdx.x & 63;
    if (lane == 0) { red[wv] = l1; red[4 + wv] = ss; }
    __syncthreads();
    if (threadIdx.x == 0) {
        const double n = 25165824.0;   // 32*3*512*512
        const double L1 = (red[0] + red[1] + red[2] + red[3]) / n;
        const double SS = (red[4] + red[5] + red[6] + red[7]) / n;
        out[0] = (float)(0.5 * L1 + 0.5 * (1.0 - SS));
    }
}

extern "C" void kernel_launch(void* const* d_in, const int* in_sizes, int n_in,
                              void* d_out, int out_size, void* d_ws, size_t ws_size,
                              hipStream_t stream)
{
    const float* warped = (const float*)d_in[0];
    const float* target = (const float*)d_in[1];
    float* out      = (float*)d_out;
    float2* partial = (float2*)d_ws;

    // Gaussian window (f32, same as reference)
    Weights wt;
    float g[11], sum = 0.0f;
    for (int i = 0; i < 11; ++i) {
        const float cc = (float)(i - 5);
        g[i] = expf(-(cc * cc) / (2.0f * 1.5f * 1.5f));
        sum += g[i];
    }
    for (int i = 0; i < 11; ++i) wt.w[i] = g[i] / sum;

    dim3 grid(5, 4, 96);    // x-tiles(116 cols) × y-groups(4 waves × 32 rows) × planes
    dim3 block(256);
    hipLaunchKernelGGL(ssim_l1_kernel, grid, block, 0, stream,
                       warped, target, partial, wt);
    hipLaunchKernelGGL(reduce_kernel, dim3(1), dim3(256), 0, stream, partial, out);
}

// Round 7
// 130.398 us; speedup vs baseline: 3.2403x; 1.0295x over previous
//
#include <hip/hip_runtime.h>
#include <math.h>

#define IMW 512
#define IMH 512
#define NPIX (IMW * IMH)
#define TR 32              // output rows per wave
#define OWMAX 116          // output cols per tile (last tile: 48)
#define NITER (TR + 10)    // 42 row iterations
#define C1F 1.0e-4f
#define C2F 9.0e-4f
#define NXT 5
#define NYT 16
#define NBLK (NXT * NYT * 96)

typedef float f2 __attribute__((ext_vector_type(2)));

struct Weights { float w[11]; };

__device__ __forceinline__ f2 splat2(float v) { f2 r; r.x = v; r.y = v; return r; }

__global__ __launch_bounds__(64)
void ssim_l1_kernel(const float* __restrict__ warped,
                    const float* __restrict__ target,
                    float2* __restrict__ partial,
                    Weights wt)
{
    const int lane  = threadIdx.x;        // 0..63 (1-wave block)
    const int bx    = blockIdx.x;         // 0..4
    const int yb    = blockIdx.y;         // 0..15
    const int plane = blockIdx.z;         // 0..95

    const int c0 = bx * OWMAX;            // output cols [c0, c0+OW)
    const int OW = min(OWMAX, IMW - c0);
    const int r0 = yb * TR;               // output rows [r0, r0+TR)
    const int colL = c0 - 6 + 2 * lane;   // first col this lane loads (even)

    // column load mask (zero-pad outside image)
    f2 cm;
    cm.x = (colL     >= 0 && colL     < IMW) ? 1.f : 0.f;
    cm.y = (colL + 1 >= 0 && colL + 1 < IMW) ? 1.f : 0.f;
    // output mask: own cols are outputs for lanes 3..60 within [c0, c0+OW)
    const bool laneOut = (lane >= 3) && (lane <= 60);
    f2 om;
    om.x = (laneOut && (colL     - c0) < OW) ? 1.f : 0.f;
    om.y = (laneOut && (colL + 1 - c0) < OW) ? 1.f : 0.f;

    const int fi = min(max(colL >> 1, 0), IMW / 2 - 1);   // clamped float2 index
    const f2* xp = (const f2*)(warped + (size_t)plane * NPIX);
    const f2* yp = (const f2*)(target + (size_t)plane * NPIX);

    // 11-slot sliding windows of horizontally-blurred quantities (f2 = 2 cols)
    f2 Wm1[11], Wm2[11], Wsq[11], Wp[11];
    f2 l12 = splat2(0.f), ssum2 = splat2(0.f);

    // prologue: issue load for iteration 0 (row r0-5, clamped)
    {
        const int rp = min(max(r0 - 5, 0), IMH - 1);
        // loads issued below in-loop style
    }
    int rp0 = min(max(r0 - 5, 0), IMH - 1);
    f2 fx = xp[rp0 * (IMW / 2) + fi];
    f2 fy = yp[rp0 * (IMW / 2) + fi];

    #pragma unroll 1
    for (int ob = 0; ob < 44; ob += 11) {
        #pragma unroll
        for (int jj = 0; jj < 11; ++jj) {
            const int i = ob + jj;        // i % 11 == jj  (since ob % 11 == 0)
            if (i < NITER) {
                // ---- consume pending load, mask to zero-pad ----
                const int rr = r0 - 5 + i;
                const float rmsk = (rr >= 0 && rr < IMH) ? 1.f : 0.f;
                const f2 cmm = cm * splat2(rmsk);
                const f2 x = fx * cmm;
                const f2 y = fy * cmm;

                // ---- L1 at consume (center rows i in [5, TR+5)) ----
                if (i >= 5 && i < TR + 5) {
                    f2 d = x - y;
                    d.x = fabsf(d.x); d.y = fabsf(d.y);
                    l12 += d * om;
                }

                // ---- prefetch next row (branchless, clamped) ----
                if (i + 1 < NITER) {
                    const int rn = min(max(r0 - 4 + i, 0), IMH - 1);
                    fx = xp[rn * (IMW / 2) + fi];
                    fy = yp[rn * (IMW / 2) + fi];
                }

                // ---- halo exchange of raw x,y via crossbar permute ----
                float qx[12], qy[12];
                qx[0]  = __shfl(x.y, lane - 3);
                qx[1]  = __shfl(x.x, lane - 2);
                qx[2]  = __shfl(x.y, lane - 2);
                qx[3]  = __shfl(x.x, lane - 1);
                qx[4]  = __shfl(x.y, lane - 1);
                qx[5]  = x.x;
                qx[6]  = x.y;
                qx[7]  = __shfl(x.x, lane + 1);
                qx[8]  = __shfl(x.y, lane + 1);
                qx[9]  = __shfl(x.x, lane + 2);
                qx[10] = __shfl(x.y, lane + 2);
                qx[11] = __shfl(x.x, lane + 3);
                qy[0]  = __shfl(y.y, lane - 3);
                qy[1]  = __shfl(y.x, lane - 2);
                qy[2]  = __shfl(y.y, lane - 2);
                qy[3]  = __shfl(y.x, lane - 1);
                qy[4]  = __shfl(y.y, lane - 1);
                qy[5]  = y.x;
                qy[6]  = y.y;
                qy[7]  = __shfl(y.x, lane + 1);
                qy[8]  = __shfl(y.y, lane + 1);
                qy[9]  = __shfl(y.x, lane + 2);
                qy[10] = __shfl(y.y, lane + 2);
                qy[11] = __shfl(y.x, lane + 3);

                // ---- derive 2nd-moment fields at all taps (lane-local) ----
                float qq[12], qp[12];
                #pragma unroll
                for (int t = 0; t < 12; ++t) {
                    qq[t] = fmaf(qx[t], qx[t], qy[t] * qy[t]);
                    qp[t] = qx[t] * qy[t];
                }

                // ---- horizontal blur, 4 quantities x 2 output cols ----
                float hm1[2], hm2[2], hq[2], hp[2];
                #pragma unroll
                for (int o = 0; o < 2; ++o) {
                    float a0 = 0.f, a1 = 0.f, a2 = 0.f, a3 = 0.f;
                    #pragma unroll
                    for (int d = 0; d < 11; ++d) {
                        const float wk = wt.w[d];
                        a0 = fmaf(wk, qx[o + d], a0);
                        a1 = fmaf(wk, qy[o + d], a1);
                        a2 = fmaf(wk, qq[o + d], a2);
                        a3 = fmaf(wk, qp[o + d], a3);
                    }
                    hm1[o] = a0; hm2[o] = a1; hq[o] = a2; hp[o] = a3;
                }
                // store into sliding window slot jj
                f2 t1; t1.x = hm1[0]; t1.y = hm1[1]; Wm1[jj] = t1;
                f2 t2; t2.x = hm2[0]; t2.y = hm2[1]; Wm2[jj] = t2;
                f2 t3; t3.x = hq[0];  t3.y = hq[1];  Wsq[jj] = t3;
                f2 t4; t4.x = hp[0];  t4.y = hp[1];  Wp[jj]  = t4;

                // ---- vertical blur (packed f32) + SSIM for row r0+(i-10) ----
                if (i >= 10) {
                    f2 Vm1 = splat2(0.f), Vm2 = splat2(0.f);
                    f2 Vq  = splat2(0.f), Vp2 = splat2(0.f);
                    #pragma unroll
                    for (int k = 0; k < 11; ++k) {
                        const int s = (jj + 1 + k) % 11;   // static after unroll
                        const f2 wk2 = splat2(wt.w[k]);
                        Vm1 = __builtin_elementwise_fma(wk2, Wm1[s], Vm1);
                        Vm2 = __builtin_elementwise_fma(wk2, Wm2[s], Vm2);
                        Vq  = __builtin_elementwise_fma(wk2, Wsq[s], Vq);
                        Vp2 = __builtin_elementwise_fma(wk2, Wp[s],  Vp2);
                    }
                    const f2 mu1sq = Vm1 * Vm1;
                    const f2 mu2sq = Vm2 * Vm2;
                    const f2 mu12  = Vm1 * Vm2;
                    const f2 s12   = Vp2 - mu12;
                    const f2 ssig  = Vq - mu1sq - mu2sq;   // sigma1^2 + sigma2^2
                    const f2 num = (splat2(2.f) * mu12 + splat2(C1F)) *
                                   (splat2(2.f) * s12  + splat2(C2F));
                    const f2 den = (mu1sq + mu2sq + splat2(C1F)) *
                                   (ssig + splat2(C2F));
                    f2 r;
                    r.x = __builtin_amdgcn_rcpf(den.x);
                    r.y = __builtin_amdgcn_rcpf(den.y);
                    ssum2 = __builtin_elementwise_fma(num * r, om, ssum2);
                }
            }
        }
    }

    // ---- wave reduction (single-wave block, no LDS, no barrier) ----
    float l1sum = l12.x + l12.y;
    float ssum  = ssum2.x + ssum2.y;
    #pragma unroll
    for (int off = 32; off > 0; off >>= 1) {
        l1sum += __shfl_down(l1sum, off);
        ssum  += __shfl_down(ssum,  off);
    }
    if (lane == 0) {
        const int bid = (blockIdx.z * gridDim.y + blockIdx.y) * gridDim.x + blockIdx.x;
        partial[bid] = make_float2(l1sum, ssum);
    }
}

__global__ __launch_bounds__(256)
void reduce_kernel(const float2* __restrict__ partial, float* __restrict__ out)
{
    double l1 = 0.0, ss = 0.0;
    for (int i = threadIdx.x; i < NBLK; i += 256) {
        const float2 p = partial[i];
        l1 += (double)p.x;
        ss += (double)p.y;
    }
    #pragma unroll
    for (int off = 32; off > 0; off >>= 1) {
        l1 += __shfl_down(l1, off);
        ss += __shfl_down(ss, off);
    }
    __shared__ double red[8];
    const int wv = threadIdx.x >> 6, lane = threadIdx.x & 63;
    if (lane == 0) { red[wv] = l1; red[4 + wv] = ss; }
    __syncthreads();
    if (threadIdx.x == 0) {
        const double n = 25165824.0;   // 32*3*512*512
        const double L1 = (red[0] + red[1] + red[2] + red[3]) / n;
        const double SS = (red[4] + red[5] + red[6] + red[7]) / n;
        out[0] = (float)(0.5 * L1 + 0.5 * (1.0 - SS));
    }
}

extern "C" void kernel_launch(void* const* d_in, const int* in_sizes, int n_in,
                              void* d_out, int out_size, void* d_ws, size_t ws_size,
                              hipStream_t stream)
{
    const float* warped = (const float*)d_in[0];
    const float* target = (const float*)d_in[1];
    float* out      = (float*)d_out;
    float2* partial = (float2*)d_ws;

    // Gaussian window (f32, same as reference)
    Weights wt;
    float g[11], sum = 0.0f;
    for (int i = 0; i < 11; ++i) {
        const float cc = (float)(i - 5);
        g[i] = expf(-(cc * cc) / (2.0f * 1.5f * 1.5f));
        sum += g[i];
    }
    for (int i = 0; i < 11; ++i) wt.w[i] = g[i] / sum;

    dim3 grid(NXT, NYT, 96);   // x-tiles(116/48 cols) × y-tiles(32 rows) × planes
    dim3 block(64);            // one wave per block
    hipLaunchKernelGGL(ssim_l1_kernel, grid, block, 0, stream,
                       warped, target, partial, wt);
    hipLaunchKernelGGL(reduce_kernel, dim3(1), dim3(256), 0, stream, partial, out);
}